// Round 1
// baseline (1484.150 us; speedup 1.0000x reference)
//
#include <hip/hip_runtime.h>
#include <hip/hip_bf16.h>

#define N_NODES 50000
#define N_EDGES 800000
#define D 128           // D_IN == D_OUT == 128
#define GEMM_ROWS 32    // rows of x per block in the GEMM

// ---------------------------------------------------------------------------
// Kernel 1: support = x @ W   (fp32, vector ALU — no fp32 MFMA on CDNA4)
// Block: 256 threads = 128 cols x 2 row-slots. Each thread computes 16 output
// elements (cols fixed = tx, rows ty + 2*i). W staged in LDS in two k-tiles
// of 64 (32 KB), x tile (32 rows x 128) staged fully (16 KB) -> 48 KB LDS.
// xs reads are wave-broadcast (all 64 lanes of a wave share ty) => conflict-free.
// ws reads: consecutive tx -> 2 lanes/bank which is free on gfx950.
// ---------------------------------------------------------------------------
__global__ __launch_bounds__(256) void gemm_xw(
    const float* __restrict__ x, const float* __restrict__ w,
    float* __restrict__ support, int n_nodes) {
  __shared__ float ws[64 * D];          // one k-tile of W
  __shared__ float xs[GEMM_ROWS * D];   // full x tile (all 128 k)

  const int tid = threadIdx.x;
  const int row0 = blockIdx.x * GEMM_ROWS;
  const int nrows = min(GEMM_ROWS, n_nodes - row0);

  // load x tile: nrows*128 floats, float4-vectorized
  {
    const float4* x4 = (const float4*)(x + (size_t)row0 * D);
    float4* xs4 = (float4*)xs;
    const int n4 = nrows * (D / 4);
    for (int i = tid; i < n4; i += 256) xs4[i] = x4[i];
  }

  const int tx = tid & 127;  // output col
  const int ty = tid >> 7;   // 0/1 row slot

  float acc[16];
#pragma unroll
  for (int i = 0; i < 16; i++) acc[i] = 0.f;

  for (int k0 = 0; k0 < D; k0 += 64) {
    __syncthreads();  // protect ws from previous tile / xs load done
    // load W k-tile: 64*128 floats = 2048 float4 / 256 threads = 8 each
    {
      const float4* w4 = (const float4*)(w + (size_t)k0 * D);
      float4* ws4 = (float4*)ws;
      for (int i = tid; i < 64 * D / 4; i += 256) ws4[i] = w4[i];
    }
    __syncthreads();

    for (int k = 0; k < 64; k++) {
      const float wv = ws[k * D + tx];
#pragma unroll
      for (int i = 0; i < 16; i++) {
        acc[i] += xs[(ty + 2 * i) * D + (k0 + k)] * wv;
      }
    }
  }

#pragma unroll
  for (int i = 0; i < 16; i++) {
    const int r = row0 + ty + 2 * i;
    if (r < n_nodes) support[(size_t)r * D + tx] = acc[i];
  }
}

// ---------------------------------------------------------------------------
// Kernel 2: out[n][d] = bias[d]  (harness re-poisons d_out each call)
// float4-vectorized: 1.6M float4 stores.
// ---------------------------------------------------------------------------
__global__ __launch_bounds__(256) void init_out(
    float* __restrict__ out, const float* __restrict__ bias, int n4) {
  const int i = blockIdx.x * 256 + threadIdx.x;
  if (i < n4) {
    ((float4*)out)[i] = ((const float4*)bias)[i & (D / 4 - 1)];
  }
}

// ---------------------------------------------------------------------------
// Kernel 3: edge scatter.  32 lanes per edge, each lane owns 4 consecutive d.
// Gather support[src[e]] (float4, coalesced 512B per edge), scale by
// edge_vals[e], atomicAdd into out[dst[e]].
// ---------------------------------------------------------------------------
__global__ __launch_bounds__(256) void edge_scatter(
    const float* __restrict__ support, const int* __restrict__ src,
    const int* __restrict__ dst, const float* __restrict__ ev,
    float* __restrict__ out, int n_edges) {
  const int g = blockIdx.x * 256 + threadIdx.x;
  const int e = g >> 5;
  const int lane = g & 31;
  if (e >= n_edges) return;

  const int s = src[e];
  const int d = dst[e];
  const float v = ev[e];

  const float4 sv = ((const float4*)(support + (size_t)s * D))[lane];
  float* op = out + (size_t)d * D + lane * 4;
  atomicAdd(op + 0, sv.x * v);
  atomicAdd(op + 1, sv.y * v);
  atomicAdd(op + 2, sv.z * v);
  atomicAdd(op + 3, sv.w * v);
}

extern "C" void kernel_launch(void* const* d_in, const int* in_sizes, int n_in,
                              void* d_out, int out_size, void* d_ws, size_t ws_size,
                              hipStream_t stream) {
  const float* x    = (const float*)d_in[0];   // [N_NODES, D]
  const float* w    = (const float*)d_in[1];   // [D, D]
  const float* bias = (const float*)d_in[2];   // [D]
  const int*   src  = (const int*)d_in[3];     // [N_EDGES]
  const int*   dst  = (const int*)d_in[4];     // [N_EDGES]
  const float* ev   = (const float*)d_in[5];   // [N_EDGES]
  float* out = (float*)d_out;                  // [N_NODES, D]

  const int n_nodes = in_sizes[0] / D;
  const int n_edges = in_sizes[3];

  float* support = (float*)d_ws;               // 25.6 MB scratch

  // 1) support = x @ W
  {
    dim3 grid((n_nodes + GEMM_ROWS - 1) / GEMM_ROWS);
    gemm_xw<<<grid, 256, 0, stream>>>(x, w, support, n_nodes);
  }

  // 2) out = bias (broadcast)
  {
    const int n4 = n_nodes * (D / 4);
    dim3 grid((n4 + 255) / 256);
    init_out<<<grid, 256, 0, stream>>>(out, bias, n4);
  }

  // 3) out[dst] += ev * support[src]
  {
    const long long total = (long long)n_edges * 32;
    dim3 grid((unsigned)((total + 255) / 256));
    edge_scatter<<<grid, 256, 0, stream>>>(support, src, dst, ev, out, n_edges);
  }
}

// Round 2
// 389.790 us; speedup vs baseline: 3.8076x; 3.8076x over previous
//
#include <hip/hip_runtime.h>
#include <hip/hip_bf16.h>

#define D 128  // D_IN == D_OUT == 128

// ---------------------------------------------------------------------------
// Kernel 1: support = x @ W  (fp32 vector ALU; no fp32 MFMA on CDNA4)
// 64 rows x 128 cols per block, 256 threads, each thread 4 rows x 8 cols.
// Per k: 4 ds_read_b32 (xs, 2-way bank alias = free) + 2 ds_read_b128 (ws)
// feeding 32 FMAs -> VALU-bound, not LDS-bound.
// xs padded to stride 132 floats: rows ty*4 apart land on distinct banks.
// ---------------------------------------------------------------------------
__global__ __launch_bounds__(256) void gemm_xw(
    const float* __restrict__ x, const float* __restrict__ w,
    float* __restrict__ support, int n_nodes) {
  __shared__ float ws[64 * D];    // 32 KB, one k-tile of W
  __shared__ float xs[64 * 132];  // 33 KB, full-k x tile, padded stride

  const int tid = threadIdx.x;
  const int row0 = blockIdx.x * 64;
  const int nrows = min(64, n_nodes - row0);

  // stage x tile (float4)
  {
    const float4* x4 = (const float4*)(x + (size_t)row0 * D);
    const int n4 = nrows * (D / 4);
    for (int i = tid; i < n4; i += 256) {
      const int r = i >> 5, c = i & 31;
      ((float4*)(xs + r * 132))[c] = x4[i];
    }
  }

  const int tx = tid & 15;  // cols tx*8 .. tx*8+7
  const int ty = tid >> 4;  // rows ty*4 .. ty*4+3

  float acc[4][8];
#pragma unroll
  for (int j = 0; j < 4; j++)
#pragma unroll
    for (int c = 0; c < 8; c++) acc[j][c] = 0.f;

  for (int k0 = 0; k0 < D; k0 += 64) {
    __syncthreads();
    {
      const float4* w4 = (const float4*)(w + (size_t)k0 * D);
      float4* ws4 = (float4*)ws;
      for (int i = tid; i < 64 * (D / 4); i += 256) ws4[i] = w4[i];
    }
    __syncthreads();

    for (int k = 0; k < 64; k++) {
      float xv[4];
#pragma unroll
      for (int j = 0; j < 4; j++) xv[j] = xs[(ty * 4 + j) * 132 + k0 + k];
      const float4 wv0 = *(const float4*)(ws + k * D + tx * 8);
      const float4 wv1 = *(const float4*)(ws + k * D + tx * 8 + 4);
#pragma unroll
      for (int j = 0; j < 4; j++) {
        acc[j][0] += xv[j] * wv0.x;
        acc[j][1] += xv[j] * wv0.y;
        acc[j][2] += xv[j] * wv0.z;
        acc[j][3] += xv[j] * wv0.w;
        acc[j][4] += xv[j] * wv1.x;
        acc[j][5] += xv[j] * wv1.y;
        acc[j][6] += xv[j] * wv1.z;
        acc[j][7] += xv[j] * wv1.w;
      }
    }
  }

#pragma unroll
  for (int j = 0; j < 4; j++) {
    const int r = row0 + ty * 4 + j;
    if (r < n_nodes) {
      float4* o = (float4*)(support + (size_t)r * D + tx * 8);
      o[0] = make_float4(acc[j][0], acc[j][1], acc[j][2], acc[j][3]);
      o[1] = make_float4(acc[j][4], acc[j][5], acc[j][6], acc[j][7]);
    }
  }
}

// ---------------------------------------------------------------------------
// CSR build: zero -> histogram -> scan -> bucket-sort (src, ev) by dst
// ---------------------------------------------------------------------------
__global__ __launch_bounds__(256) void zero_i32(int* __restrict__ p, int n) {
  const int i = blockIdx.x * 256 + threadIdx.x;
  if (i < n) p[i] = 0;
}

__global__ __launch_bounds__(256) void hist_dst(
    const int* __restrict__ dst, int* __restrict__ deg, int n_edges) {
  const int e = blockIdx.x * 256 + threadIdx.x;
  if (e < n_edges) atomicAdd(&deg[dst[e]], 1);
}

// single-block exclusive scan over deg[0..n) -> off[0..n], cur[0..n)
__global__ __launch_bounds__(1024) void scan_deg(
    const int* __restrict__ deg, int* __restrict__ off, int* __restrict__ cur,
    int n) {
  __shared__ int lds[1024];
  const int t = threadIdx.x;
  const int chunk = (n + 1023) / 1024;
  const int base = t * chunk;

  int s = 0;
  for (int j = 0; j < chunk; j++) {
    const int idx = base + j;
    if (idx < n) s += deg[idx];
  }
  lds[t] = s;
  __syncthreads();
  for (int ofs = 1; ofs < 1024; ofs <<= 1) {
    const int v = (t >= ofs) ? lds[t - ofs] : 0;
    __syncthreads();
    lds[t] += v;
    __syncthreads();
  }
  int run = lds[t] - s;  // exclusive prefix for this chunk
  for (int j = 0; j < chunk; j++) {
    const int idx = base + j;
    if (idx < n) {
      off[idx] = run;
      cur[idx] = run;
      run += deg[idx];
    }
  }
  if (t == 1023) off[n] = lds[1023];
}

__global__ __launch_bounds__(256) void sort_edges(
    const int* __restrict__ src, const int* __restrict__ dst,
    const float* __restrict__ ev, int* __restrict__ cur,
    int* __restrict__ srcs, float* __restrict__ evs, int n_edges) {
  const int e = blockIdx.x * 256 + threadIdx.x;
  if (e < n_edges) {
    const int p = atomicAdd(&cur[dst[e]], 1);
    srcs[p] = src[e];
    evs[p] = ev[e];
  }
}

// ---------------------------------------------------------------------------
// Gather-reduce: 32 lanes per dst node (each lane owns one float4 of D=128).
// out[d] = bias + sum_{i in [off[d],off[d+1])} evs[i] * support[srcs[i]]
// Atomic-free; every out element written exactly once (bias fused).
// ---------------------------------------------------------------------------
__global__ __launch_bounds__(256) void gather_nodes(
    const float* __restrict__ support, const int* __restrict__ off,
    const int* __restrict__ srcs, const float* __restrict__ evs,
    const float* __restrict__ bias, float* __restrict__ out, int n_nodes) {
  const int d = blockIdx.x * 8 + (threadIdx.x >> 5);
  const int lane = threadIdx.x & 31;
  if (d >= n_nodes) return;

  const int beg = off[d];
  const int end = off[d + 1];
  const float4* sup4 = (const float4*)support;

  float4 acc = make_float4(0.f, 0.f, 0.f, 0.f);
  int i = beg;
  for (; i + 2 <= end; i += 2) {
    const int s0 = srcs[i], s1 = srcs[i + 1];
    const float v0 = evs[i], v1 = evs[i + 1];
    const float4 a = sup4[(size_t)s0 * 32 + lane];
    const float4 b = sup4[(size_t)s1 * 32 + lane];
    acc.x += a.x * v0 + b.x * v1;
    acc.y += a.y * v0 + b.y * v1;
    acc.z += a.z * v0 + b.z * v1;
    acc.w += a.w * v0 + b.w * v1;
  }
  if (i < end) {
    const int s0 = srcs[i];
    const float v0 = evs[i];
    const float4 a = sup4[(size_t)s0 * 32 + lane];
    acc.x += a.x * v0;
    acc.y += a.y * v0;
    acc.z += a.z * v0;
    acc.w += a.w * v0;
  }

  const float4 bv = ((const float4*)bias)[lane];
  ((float4*)out)[(size_t)d * 32 + lane] =
      make_float4(acc.x + bv.x, acc.y + bv.y, acc.z + bv.z, acc.w + bv.w);
}

extern "C" void kernel_launch(void* const* d_in, const int* in_sizes, int n_in,
                              void* d_out, int out_size, void* d_ws, size_t ws_size,
                              hipStream_t stream) {
  const float* x    = (const float*)d_in[0];
  const float* w    = (const float*)d_in[1];
  const float* bias = (const float*)d_in[2];
  const int*   src  = (const int*)d_in[3];
  const int*   dst  = (const int*)d_in[4];
  const float* ev   = (const float*)d_in[5];
  float* out = (float*)d_out;

  const int n_nodes = in_sizes[0] / D;
  const int n_edges = in_sizes[3];

  // workspace layout (16B-aligned chunks)
  const size_t nn_pad = ((size_t)n_nodes + 16) & ~15ULL;  // room for off[n]
  float* support = (float*)d_ws;                       // n_nodes*D floats
  int* deg  = (int*)(support + (size_t)n_nodes * D);   // nn_pad
  int* off  = deg + nn_pad;                            // nn_pad (incl off[n])
  int* cur  = off + nn_pad;                            // nn_pad
  int* srcs = cur + nn_pad;                            // n_edges
  float* evs = (float*)(srcs + n_edges);               // n_edges

  const int eb = (n_edges + 255) / 256;

  // CSR build
  zero_i32<<<(n_nodes + 255) / 256, 256, 0, stream>>>(deg, n_nodes);
  hist_dst<<<eb, 256, 0, stream>>>(dst, deg, n_edges);
  scan_deg<<<1, 1024, 0, stream>>>(deg, off, cur, n_nodes);
  sort_edges<<<eb, 256, 0, stream>>>(src, dst, ev, cur, srcs, evs, n_edges);

  // dense projection
  gemm_xw<<<(n_nodes + 63) / 64, 256, 0, stream>>>(x, w, support, n_nodes);

  // gather-reduce (+bias), atomic-free
  gather_nodes<<<(n_nodes + 7) / 8, 256, 0, stream>>>(
      support, off, srcs, evs, bias, out, n_nodes);
}

// Round 3
// 271.340 us; speedup vs baseline: 5.4697x; 1.4365x over previous
//
#include <hip/hip_runtime.h>
#include <hip/hip_bf16.h>

#define D 128  // D_IN == D_OUT == 128

// ---------------------------------------------------------------------------
// Kernel 1: support = x @ W  (fp32 vector ALU; no fp32 MFMA on CDNA4)
// 64 rows x 128 cols per block, 256 threads, each thread 4 rows x 8 cols.
// ---------------------------------------------------------------------------
__global__ __launch_bounds__(256) void gemm_xw(
    const float* __restrict__ x, const float* __restrict__ w,
    float* __restrict__ support, int n_nodes) {
  __shared__ float ws[64 * D];    // 32 KB, one k-tile of W
  __shared__ float xs[64 * 132];  // 33 KB, full-k x tile, padded stride

  const int tid = threadIdx.x;
  const int row0 = blockIdx.x * 64;
  const int nrows = min(64, n_nodes - row0);

  {
    const float4* x4 = (const float4*)(x + (size_t)row0 * D);
    const int n4 = nrows * (D / 4);
    for (int i = tid; i < n4; i += 256) {
      const int r = i >> 5, c = i & 31;
      ((float4*)(xs + r * 132))[c] = x4[i];
    }
  }

  const int tx = tid & 15;  // cols tx*8 .. tx*8+7
  const int ty = tid >> 4;  // rows ty*4 .. ty*4+3

  float acc[4][8];
#pragma unroll
  for (int j = 0; j < 4; j++)
#pragma unroll
    for (int c = 0; c < 8; c++) acc[j][c] = 0.f;

  for (int k0 = 0; k0 < D; k0 += 64) {
    __syncthreads();
    {
      const float4* w4 = (const float4*)(w + (size_t)k0 * D);
      float4* ws4 = (float4*)ws;
      for (int i = tid; i < 64 * (D / 4); i += 256) ws4[i] = w4[i];
    }
    __syncthreads();

    for (int k = 0; k < 64; k++) {
      float xv[4];
#pragma unroll
      for (int j = 0; j < 4; j++) xv[j] = xs[(ty * 4 + j) * 132 + k0 + k];
      const float4 wv0 = *(const float4*)(ws + k * D + tx * 8);
      const float4 wv1 = *(const float4*)(ws + k * D + tx * 8 + 4);
#pragma unroll
      for (int j = 0; j < 4; j++) {
        acc[j][0] += xv[j] * wv0.x;
        acc[j][1] += xv[j] * wv0.y;
        acc[j][2] += xv[j] * wv0.z;
        acc[j][3] += xv[j] * wv0.w;
        acc[j][4] += xv[j] * wv1.x;
        acc[j][5] += xv[j] * wv1.y;
        acc[j][6] += xv[j] * wv1.z;
        acc[j][7] += xv[j] * wv1.w;
      }
    }
  }

#pragma unroll
  for (int j = 0; j < 4; j++) {
    const int r = row0 + ty * 4 + j;
    if (r < n_nodes) {
      float4* o = (float4*)(support + (size_t)r * D + tx * 8);
      o[0] = make_float4(acc[j][0], acc[j][1], acc[j][2], acc[j][3]);
      o[1] = make_float4(acc[j][4], acc[j][5], acc[j][6], acc[j][7]);
    }
  }
}

// ---------------------------------------------------------------------------
// CSR build: memset -> histogram -> 3-phase multi-block scan -> bucket sort.
// Scan layout: 4096 elems/block (256 thr x 16 = one 64B line per thread).
// ---------------------------------------------------------------------------
__global__ __launch_bounds__(256) void hist_dst(
    const int* __restrict__ dst, int* __restrict__ deg, int n_edges) {
  const int e = blockIdx.x * 256 + threadIdx.x;
  if (e < n_edges) atomicAdd(&deg[dst[e]], 1);
}

// Phase A: per-block sum of 4096 deg entries -> bsum[block]
__global__ __launch_bounds__(256) void scan_block_sums(
    const int* __restrict__ deg, int* __restrict__ bsum, int n) {
  __shared__ int lds[256];
  const int t = threadIdx.x;
  const int base = blockIdx.x * 4096 + t * 16;
  int s = 0;
#pragma unroll
  for (int j = 0; j < 16; j++) {
    const int idx = base + j;
    if (idx < n) s += deg[idx];
  }
  lds[t] = s;
  __syncthreads();
  for (int ofs = 128; ofs > 0; ofs >>= 1) {
    if (t < ofs) lds[t] += lds[t + ofs];
    __syncthreads();
  }
  if (t == 0) bsum[blockIdx.x] = lds[0];
}

// Phase B: exclusive-scan bsum[0..nblocks) in one small block; write off[n].
__global__ __launch_bounds__(64) void scan_bsums(
    int* __restrict__ bsum, int* __restrict__ off, int n, int nblocks) {
  __shared__ int lds[64];
  const int t = threadIdx.x;
  int v = (t < nblocks) ? bsum[t] : 0;
  lds[t] = v;
  __syncthreads();
  for (int ofs = 1; ofs < 64; ofs <<= 1) {
    const int u = (t >= ofs) ? lds[t - ofs] : 0;
    __syncthreads();
    lds[t] += u;
    __syncthreads();
  }
  if (t < nblocks) bsum[t] = lds[t] - v;  // exclusive
  if (t == 63) off[n] = lds[63];          // grand total
}

// Phase C: local exclusive scan + block offset; writes off[] and cur[]
// (cur aliases deg -- each idx read-then-written by exactly one thread).
__global__ __launch_bounds__(256) void scan_chunks(
    const int* __restrict__ deg, const int* __restrict__ bsum,
    int* __restrict__ off, int* __restrict__ cur, int n) {
  __shared__ int lds[256];
  const int t = threadIdx.x;
  const int base = blockIdx.x * 4096 + t * 16;
  int v[16];
  int s = 0;
#pragma unroll
  for (int j = 0; j < 16; j++) {
    const int idx = base + j;
    v[j] = (idx < n) ? deg[idx] : 0;
    s += v[j];
  }
  lds[t] = s;
  __syncthreads();
  for (int ofs = 1; ofs < 256; ofs <<= 1) {
    const int u = (t >= ofs) ? lds[t - ofs] : 0;
    __syncthreads();
    lds[t] += u;
    __syncthreads();
  }
  int run = bsum[blockIdx.x] + lds[t] - s;  // exclusive prefix at base
#pragma unroll
  for (int j = 0; j < 16; j++) {
    const int idx = base + j;
    if (idx < n) {
      off[idx] = run;
      cur[idx] = run;
      run += v[j];
    }
  }
}

// Bucket sort: (src, ev) packed as int2 -> one 8B random store per edge.
__global__ __launch_bounds__(256) void sort_edges(
    const int* __restrict__ src, const int* __restrict__ dst,
    const float* __restrict__ ev, int* __restrict__ cur,
    int2* __restrict__ pairs, int n_edges) {
  const int e = blockIdx.x * 256 + threadIdx.x;
  if (e < n_edges) {
    const int p = atomicAdd(&cur[dst[e]], 1);
    pairs[p] = make_int2(src[e], __float_as_int(ev[e]));
  }
}

// ---------------------------------------------------------------------------
// Gather-reduce: 32 lanes per dst node (each lane owns one float4 of D=128).
// out[d] = bias + sum_i ev_i * support[src_i]; atomic-free, bias fused.
// ---------------------------------------------------------------------------
__global__ __launch_bounds__(256) void gather_nodes(
    const float* __restrict__ support, const int* __restrict__ off,
    const int2* __restrict__ pairs, const float* __restrict__ bias,
    float* __restrict__ out, int n_nodes) {
  const int d = blockIdx.x * 8 + (threadIdx.x >> 5);
  const int lane = threadIdx.x & 31;
  if (d >= n_nodes) return;

  const int beg = off[d];
  const int end = off[d + 1];
  const float4* sup4 = (const float4*)support;

  float4 acc = make_float4(0.f, 0.f, 0.f, 0.f);
  int i = beg;
  for (; i + 2 <= end; i += 2) {
    const int2 p0 = pairs[i];
    const int2 p1 = pairs[i + 1];
    const float v0 = __int_as_float(p0.y);
    const float v1 = __int_as_float(p1.y);
    const float4 a = sup4[(size_t)p0.x * 32 + lane];
    const float4 b = sup4[(size_t)p1.x * 32 + lane];
    acc.x += a.x * v0 + b.x * v1;
    acc.y += a.y * v0 + b.y * v1;
    acc.z += a.z * v0 + b.z * v1;
    acc.w += a.w * v0 + b.w * v1;
  }
  if (i < end) {
    const int2 p0 = pairs[i];
    const float v0 = __int_as_float(p0.y);
    const float4 a = sup4[(size_t)p0.x * 32 + lane];
    acc.x += a.x * v0;
    acc.y += a.y * v0;
    acc.z += a.z * v0;
    acc.w += a.w * v0;
  }

  const float4 bv = ((const float4*)bias)[lane];
  ((float4*)out)[(size_t)d * 32 + lane] =
      make_float4(acc.x + bv.x, acc.y + bv.y, acc.z + bv.z, acc.w + bv.w);
}

extern "C" void kernel_launch(void* const* d_in, const int* in_sizes, int n_in,
                              void* d_out, int out_size, void* d_ws, size_t ws_size,
                              hipStream_t stream) {
  const float* x    = (const float*)d_in[0];
  const float* w    = (const float*)d_in[1];
  const float* bias = (const float*)d_in[2];
  const int*   src  = (const int*)d_in[3];
  const int*   dst  = (const int*)d_in[4];
  const float* ev   = (const float*)d_in[5];
  float* out = (float*)d_out;

  const int n_nodes = in_sizes[0] / D;
  const int n_edges = in_sizes[3];

  // workspace layout (all offsets 8B-aligned)
  const size_t nn_pad = ((size_t)n_nodes + 16) & ~15ULL;  // room for off[n]
  float* support = (float*)d_ws;                        // n_nodes*D floats
  int* deg  = (int*)(support + (size_t)n_nodes * D);    // nn_pad (doubles as cur)
  int* off  = deg + nn_pad;                             // nn_pad (incl off[n])
  int* bsum = off + nn_pad;                             // 64
  int2* pairs = (int2*)(bsum + 64);                     // n_edges int2

  const int eb = (n_edges + 255) / 256;
  const int sblocks = (n_nodes + 4095) / 4096;  // 13 for 50K

  // CSR build
  hipMemsetAsync(deg, 0, n_nodes * sizeof(int), stream);
  hist_dst<<<eb, 256, 0, stream>>>(dst, deg, n_edges);
  scan_block_sums<<<sblocks, 256, 0, stream>>>(deg, bsum, n_nodes);
  scan_bsums<<<1, 64, 0, stream>>>(bsum, off, n_nodes, sblocks);
  scan_chunks<<<sblocks, 256, 0, stream>>>(deg, bsum, off, /*cur=*/deg, n_nodes);
  sort_edges<<<eb, 256, 0, stream>>>(src, dst, ev, /*cur=*/deg, pairs, n_edges);

  // dense projection
  gemm_xw<<<(n_nodes + 63) / 64, 256, 0, stream>>>(x, w, support, n_nodes);

  // gather-reduce (+bias), atomic-free
  gather_nodes<<<(n_nodes + 7) / 8, 256, 0, stream>>>(
      support, off, pairs, bias, out, n_nodes);
}

// Round 4
// 241.417 us; speedup vs baseline: 6.1477x; 1.1239x over previous
//
#include <hip/hip_runtime.h>
#include <hip/hip_bf16.h>

#define D 128  // D_IN == D_OUT == 128

typedef __attribute__((ext_vector_type(8))) short bf16x8;
typedef __attribute__((ext_vector_type(4))) float f32x4;

__device__ __forceinline__ unsigned short f2bf(float f) {
  union { float f; unsigned u; } c; c.f = f;
  unsigned u = c.u + 0x7FFFu + ((c.u >> 16) & 1u);  // RNE
  return (unsigned short)(u >> 16);
}
__device__ __forceinline__ float bf_lo(unsigned u) {
  union { unsigned u; float f; } c; c.u = u << 16; return c.f;
}
__device__ __forceinline__ float bf_hi(unsigned u) {
  union { unsigned u; float f; } c; c.u = u & 0xFFFF0000u; return c.f;
}

// ---------------------------------------------------------------------------
// W [128k x 128n] fp32 -> wT [128n x 128k] bf16 (so B-fragments are contiguous)
// ---------------------------------------------------------------------------
__global__ __launch_bounds__(256) void conv_wT(
    const float* __restrict__ w, unsigned short* __restrict__ wT) {
  const int idx = blockIdx.x * 256 + threadIdx.x;  // 16384 elements
  const int k = idx >> 7, n = idx & 127;
  wT[n * D + k] = f2bf(w[idx]);
}

// ---------------------------------------------------------------------------
// support(bf16) = x @ W via mfma_f32_16x16x32_bf16.
// Block: 256 thr = 4 waves; tile 64 rows x 128 cols, full K=128 in LDS.
// A-frag: lane m=lane&15, k=quad*8+j (verified m89); B-frag from wT rows.
// C/D: col=lane&15, row=quad*4+reg (verified m89/m91).
// xs stride 136 bf16 (272 B): a-frag ds_read_b128 lands 2-way/bank = free.
// ---------------------------------------------------------------------------
__global__ __launch_bounds__(256) void gemm_xw_mfma(
    const float* __restrict__ x, const unsigned short* __restrict__ wT,
    unsigned short* __restrict__ supb, int n_nodes) {
  __shared__ unsigned short xs[64 * 136];  // 17.4 KB

  const int tid = threadIdx.x;
  const int row0 = blockIdx.x * 64;

  // stage x tile, fp32 -> bf16 (zero-fill rows past n_nodes)
  for (int f = tid; f < 64 * 32; f += 256) {
    const int r = f >> 5, c4 = f & 31;
    const int gr = row0 + r;
    float4 v = make_float4(0.f, 0.f, 0.f, 0.f);
    if (gr < n_nodes) v = ((const float4*)(x + (size_t)gr * D))[c4];
    ushort4 b;
    b.x = f2bf(v.x); b.y = f2bf(v.y); b.z = f2bf(v.z); b.w = f2bf(v.w);
    *(ushort4*)(&xs[r * 136 + c4 * 4]) = b;
  }
  __syncthreads();

  const int wv = tid >> 6;        // wave id: rows 16*wv .. 16*wv+15
  const int lane = tid & 63;
  const int l15 = lane & 15;
  const int quad = lane >> 4;

  f32x4 acc[8];
#pragma unroll
  for (int t = 0; t < 8; t++) acc[t] = (f32x4){0.f, 0.f, 0.f, 0.f};

#pragma unroll
  for (int k0 = 0; k0 < D; k0 += 32) {
    const bf16x8 a = *(const bf16x8*)(&xs[(wv * 16 + l15) * 136 + k0 + quad * 8]);
    const unsigned short* wp = wT + (size_t)l15 * D + k0 + quad * 8;
#pragma unroll
    for (int t = 0; t < 8; t++) {
      const bf16x8 b = *(const bf16x8*)(wp + (size_t)t * 16 * D);
      acc[t] = __builtin_amdgcn_mfma_f32_16x16x32_bf16(a, b, acc[t], 0, 0, 0);
    }
  }

#pragma unroll
  for (int t = 0; t < 8; t++) {
    const int col = t * 16 + l15;
#pragma unroll
    for (int r = 0; r < 4; r++) {
      const int row = row0 + wv * 16 + quad * 4 + r;
      if (row < n_nodes) supb[(size_t)row * D + col] = f2bf(acc[t][r]);
    }
  }
}

// ---------------------------------------------------------------------------
// CSR build: memset -> histogram -> 3-phase multi-block scan -> bucket sort.
// ---------------------------------------------------------------------------
__global__ __launch_bounds__(256) void hist_dst(
    const int* __restrict__ dst, int* __restrict__ deg, int n_edges) {
  const int e = blockIdx.x * 256 + threadIdx.x;
  if (e < n_edges) atomicAdd(&deg[dst[e]], 1);
}

__global__ __launch_bounds__(256) void scan_block_sums(
    const int* __restrict__ deg, int* __restrict__ bsum, int n) {
  __shared__ int lds[256];
  const int t = threadIdx.x;
  const int base = blockIdx.x * 4096 + t * 16;
  int s = 0;
#pragma unroll
  for (int j = 0; j < 16; j++) {
    const int idx = base + j;
    if (idx < n) s += deg[idx];
  }
  lds[t] = s;
  __syncthreads();
  for (int ofs = 128; ofs > 0; ofs >>= 1) {
    if (t < ofs) lds[t] += lds[t + ofs];
    __syncthreads();
  }
  if (t == 0) bsum[blockIdx.x] = lds[0];
}

__global__ __launch_bounds__(64) void scan_bsums(
    int* __restrict__ bsum, int* __restrict__ off, int n, int nblocks) {
  __shared__ int lds[64];
  const int t = threadIdx.x;
  int v = (t < nblocks) ? bsum[t] : 0;
  lds[t] = v;
  __syncthreads();
  for (int ofs = 1; ofs < 64; ofs <<= 1) {
    const int u = (t >= ofs) ? lds[t - ofs] : 0;
    __syncthreads();
    lds[t] += u;
    __syncthreads();
  }
  if (t < nblocks) bsum[t] = lds[t] - v;  // exclusive
  if (t == 63) off[n] = lds[63];          // grand total
}

__global__ __launch_bounds__(256) void scan_chunks(
    const int* __restrict__ deg, const int* __restrict__ bsum,
    int* __restrict__ off, int* __restrict__ cur, int n) {
  __shared__ int lds[256];
  const int t = threadIdx.x;
  const int base = blockIdx.x * 4096 + t * 16;
  int v[16];
  int s = 0;
#pragma unroll
  for (int j = 0; j < 16; j++) {
    const int idx = base + j;
    v[j] = (idx < n) ? deg[idx] : 0;
    s += v[j];
  }
  lds[t] = s;
  __syncthreads();
  for (int ofs = 1; ofs < 256; ofs <<= 1) {
    const int u = (t >= ofs) ? lds[t - ofs] : 0;
    __syncthreads();
    lds[t] += u;
    __syncthreads();
  }
  int run = bsum[blockIdx.x] + lds[t] - s;
#pragma unroll
  for (int j = 0; j < 16; j++) {
    const int idx = base + j;
    if (idx < n) {
      off[idx] = run;
      cur[idx] = run;
      run += v[j];
    }
  }
}

__global__ __launch_bounds__(256) void sort_edges(
    const int* __restrict__ src, const int* __restrict__ dst,
    const float* __restrict__ ev, int* __restrict__ cur,
    int2* __restrict__ pairs, int n_edges) {
  const int e = blockIdx.x * 256 + threadIdx.x;
  if (e < n_edges) {
    const int p = atomicAdd(&cur[dst[e]], 1);
    pairs[p] = make_int2(src[e], __float_as_int(ev[e]));
  }
}

// ---------------------------------------------------------------------------
// Gather-reduce over bf16 support: 32 lanes per dst node, lane owns 4 cols.
// out[d] = bias + sum_i ev_i * support[src_i]; fp32 accumulate, atomic-free.
// ---------------------------------------------------------------------------
__global__ __launch_bounds__(256) void gather_nodes(
    const unsigned short* __restrict__ supb, const int* __restrict__ off,
    const int2* __restrict__ pairs, const float* __restrict__ bias,
    float* __restrict__ out, int n_nodes) {
  const int d = blockIdx.x * 8 + (threadIdx.x >> 5);
  const int lane = threadIdx.x & 31;  // cols lane*4 .. lane*4+3
  if (d >= n_nodes) return;

  const int beg = off[d];
  const int end = off[d + 1];
  const uint2* sup = (const uint2*)supb;  // 8 B = 4 bf16; row = 32 uint2

  float a0 = 0.f, a1 = 0.f, a2 = 0.f, a3 = 0.f;
  int i = beg;
  for (; i + 2 <= end; i += 2) {
    const int2 p0 = pairs[i];
    const int2 p1 = pairs[i + 1];
    const uint2 r0 = sup[(size_t)p0.x * 32 + lane];
    const uint2 r1 = sup[(size_t)p1.x * 32 + lane];
    const float v0 = __int_as_float(p0.y);
    const float v1 = __int_as_float(p1.y);
    a0 += v0 * bf_lo(r0.x) + v1 * bf_lo(r1.x);
    a1 += v0 * bf_hi(r0.x) + v1 * bf_hi(r1.x);
    a2 += v0 * bf_lo(r0.y) + v1 * bf_lo(r1.y);
    a3 += v0 * bf_hi(r0.y) + v1 * bf_hi(r1.y);
  }
  if (i < end) {
    const int2 p0 = pairs[i];
    const uint2 r0 = sup[(size_t)p0.x * 32 + lane];
    const float v0 = __int_as_float(p0.y);
    a0 += v0 * bf_lo(r0.x);
    a1 += v0 * bf_hi(r0.x);
    a2 += v0 * bf_lo(r0.y);
    a3 += v0 * bf_hi(r0.y);
  }

  const float4 bv = ((const float4*)bias)[lane];
  ((float4*)out)[(size_t)d * 32 + lane] =
      make_float4(a0 + bv.x, a1 + bv.y, a2 + bv.z, a3 + bv.w);
}

extern "C" void kernel_launch(void* const* d_in, const int* in_sizes, int n_in,
                              void* d_out, int out_size, void* d_ws, size_t ws_size,
                              hipStream_t stream) {
  const float* x    = (const float*)d_in[0];
  const float* w    = (const float*)d_in[1];
  const float* bias = (const float*)d_in[2];
  const int*   src  = (const int*)d_in[3];
  const int*   dst  = (const int*)d_in[4];
  const float* ev   = (const float*)d_in[5];
  float* out = (float*)d_out;

  const int n_nodes = in_sizes[0] / D;
  const int n_edges = in_sizes[3];

  // workspace layout (16B-aligned chunks)
  const size_t nn_pad = ((size_t)n_nodes + 16) & ~15ULL;
  unsigned short* supb = (unsigned short*)d_ws;        // n_nodes*D bf16
  unsigned short* wT = supb + (size_t)n_nodes * D;     // D*D bf16 (32 KB)
  int* deg  = (int*)(wT + D * D);                      // nn_pad (doubles as cur)
  int* off  = deg + nn_pad;                            // nn_pad (incl off[n])
  int* bsum = off + nn_pad;                            // 64
  int2* pairs = (int2*)(bsum + 64);                    // n_edges int2

  const int eb = (n_edges + 255) / 256;
  const int sblocks = (n_nodes + 4095) / 4096;

  // CSR build
  hipMemsetAsync(deg, 0, n_nodes * sizeof(int), stream);
  hist_dst<<<eb, 256, 0, stream>>>(dst, deg, n_edges);
  scan_block_sums<<<sblocks, 256, 0, stream>>>(deg, bsum, n_nodes);
  scan_bsums<<<1, 64, 0, stream>>>(bsum, off, n_nodes, sblocks);
  scan_chunks<<<sblocks, 256, 0, stream>>>(deg, bsum, off, /*cur=*/deg, n_nodes);
  sort_edges<<<eb, 256, 0, stream>>>(src, dst, ev, /*cur=*/deg, pairs, n_edges);

  // dense projection (bf16 MFMA)
  conv_wT<<<(D * D + 255) / 256, 256, 0, stream>>>(w, wT);
  gemm_xw_mfma<<<(n_nodes + 63) / 64, 256, 0, stream>>>(x, wT, supb, n_nodes);

  // gather-reduce (+bias), atomic-free
  gather_nodes<<<(n_nodes + 7) / 8, 256, 0, stream>>>(
      supb, off, pairs, bias, out, n_nodes);
}

// Round 5
// 223.738 us; speedup vs baseline: 6.6334x; 1.0790x over previous
//
#include <hip/hip_runtime.h>
#include <hip/hip_bf16.h>

#define D 128  // D_IN == D_OUT == 128
#define SC_EPB 4096  // edges per bucket_scatter block

typedef __attribute__((ext_vector_type(8))) short bf16x8;
typedef __attribute__((ext_vector_type(4))) float f32x4;

__device__ __forceinline__ unsigned short f2bf(float f) {
  union { float f; unsigned u; } c; c.f = f;
  unsigned u = c.u + 0x7FFFu + ((c.u >> 16) & 1u);  // RNE
  return (unsigned short)(u >> 16);
}
__device__ __forceinline__ float bf_lo(unsigned u) {
  union { unsigned u; float f; } c; c.u = u << 16; return c.f;
}
__device__ __forceinline__ float bf_hi(unsigned u) {
  union { unsigned u; float f; } c; c.u = u & 0xFFFF0000u; return c.f;
}

// ---------------------------------------------------------------------------
// W [128k x 128n] fp32 -> wT [128n x 128k] bf16
// ---------------------------------------------------------------------------
__global__ __launch_bounds__(256) void conv_wT(
    const float* __restrict__ w, unsigned short* __restrict__ wT) {
  const int idx = blockIdx.x * 256 + threadIdx.x;  // 16384 elements
  const int k = idx >> 7, n = idx & 127;
  wT[n * D + k] = f2bf(w[idx]);
}

// ---------------------------------------------------------------------------
// support(bf16) = x @ W via mfma_f32_16x16x32_bf16 (layouts verified m89/m91).
// ---------------------------------------------------------------------------
__global__ __launch_bounds__(256) void gemm_xw_mfma(
    const float* __restrict__ x, const unsigned short* __restrict__ wT,
    unsigned short* __restrict__ supb, int n_nodes) {
  __shared__ unsigned short xs[64 * 136];  // 17.4 KB

  const int tid = threadIdx.x;
  const int row0 = blockIdx.x * 64;

  for (int f = tid; f < 64 * 32; f += 256) {
    const int r = f >> 5, c4 = f & 31;
    const int gr = row0 + r;
    float4 v = make_float4(0.f, 0.f, 0.f, 0.f);
    if (gr < n_nodes) v = ((const float4*)(x + (size_t)gr * D))[c4];
    ushort4 b;
    b.x = f2bf(v.x); b.y = f2bf(v.y); b.z = f2bf(v.z); b.w = f2bf(v.w);
    *(ushort4*)(&xs[r * 136 + c4 * 4]) = b;
  }
  __syncthreads();

  const int wv = tid >> 6;
  const int lane = tid & 63;
  const int l15 = lane & 15;
  const int quad = lane >> 4;

  f32x4 acc[8];
#pragma unroll
  for (int t = 0; t < 8; t++) acc[t] = (f32x4){0.f, 0.f, 0.f, 0.f};

#pragma unroll
  for (int k0 = 0; k0 < D; k0 += 32) {
    const bf16x8 a = *(const bf16x8*)(&xs[(wv * 16 + l15) * 136 + k0 + quad * 8]);
    const unsigned short* wp = wT + (size_t)l15 * D + k0 + quad * 8;
#pragma unroll
    for (int t = 0; t < 8; t++) {
      const bf16x8 b = *(const bf16x8*)(wp + (size_t)t * 16 * D);
      acc[t] = __builtin_amdgcn_mfma_f32_16x16x32_bf16(a, b, acc[t], 0, 0, 0);
    }
  }

#pragma unroll
  for (int t = 0; t < 8; t++) {
    const int col = t * 16 + l15;
#pragma unroll
    for (int r = 0; r < 4; r++) {
      const int row = row0 + wv * 16 + quad * 4 + r;
      if (row < n_nodes) supb[(size_t)row * D + col] = f2bf(acc[t][r]);
    }
  }
}

// ---------------------------------------------------------------------------
// CSR build: memset -> histogram -> 3-phase scan -> 2-phase bucket sort.
// ---------------------------------------------------------------------------
__global__ __launch_bounds__(256) void hist_dst(
    const int* __restrict__ dst, int* __restrict__ deg, int n_edges) {
  const int e = blockIdx.x * 256 + threadIdx.x;
  if (e < n_edges) atomicAdd(&deg[dst[e]], 1);
}

__global__ __launch_bounds__(256) void scan_block_sums(
    const int* __restrict__ deg, int* __restrict__ bsum, int n) {
  __shared__ int lds[256];
  const int t = threadIdx.x;
  const int base = blockIdx.x * 4096 + t * 16;
  int s = 0;
#pragma unroll
  for (int j = 0; j < 16; j++) {
    const int idx = base + j;
    if (idx < n) s += deg[idx];
  }
  lds[t] = s;
  __syncthreads();
  for (int ofs = 128; ofs > 0; ofs >>= 1) {
    if (t < ofs) lds[t] += lds[t + ofs];
    __syncthreads();
  }
  if (t == 0) bsum[blockIdx.x] = lds[0];
}

__global__ __launch_bounds__(64) void scan_bsums(
    int* __restrict__ bsum, int* __restrict__ off, int n, int nblocks) {
  __shared__ int lds[64];
  const int t = threadIdx.x;
  int v = (t < nblocks) ? bsum[t] : 0;
  lds[t] = v;
  __syncthreads();
  for (int ofs = 1; ofs < 64; ofs <<= 1) {
    const int u = (t >= ofs) ? lds[t - ofs] : 0;
    __syncthreads();
    lds[t] += u;
    __syncthreads();
  }
  if (t < nblocks) bsum[t] = lds[t] - v;  // exclusive
  if (t == 63) off[n] = lds[63];          // grand total
}

// Phase C: writes off[] and bucket bases bcur[b] = off[b<<8].
__global__ __launch_bounds__(256) void scan_chunks(
    const int* __restrict__ deg, const int* __restrict__ bsum,
    int* __restrict__ off, int* __restrict__ bcur, int n) {
  __shared__ int lds[256];
  const int t = threadIdx.x;
  const int base = blockIdx.x * 4096 + t * 16;
  int v[16];
  int s = 0;
#pragma unroll
  for (int j = 0; j < 16; j++) {
    const int idx = base + j;
    v[j] = (idx < n) ? deg[idx] : 0;
    s += v[j];
  }
  lds[t] = s;
  __syncthreads();
  for (int ofs = 1; ofs < 256; ofs <<= 1) {
    const int u = (t >= ofs) ? lds[t - ofs] : 0;
    __syncthreads();
    lds[t] += u;
    __syncthreads();
  }
  int run = bsum[blockIdx.x] + lds[t] - s;
#pragma unroll
  for (int j = 0; j < 16; j++) {
    const int idx = base + j;
    if (idx < n) {
      off[idx] = run;
      if ((idx & 255) == 0) bcur[idx >> 8] = run;
      run += v[j];
    }
  }
}

// Bucket phase 1: block-aggregated scatter into coarse buckets (dst>>8).
// Each block claims contiguous per-bucket slots -> line-dense stores.
__global__ __launch_bounds__(256) void bucket_scatter(
    const int* __restrict__ src, const int* __restrict__ dst,
    const float* __restrict__ ev, int* __restrict__ bcur,
    int2* __restrict__ staged_pair, int* __restrict__ staged_dst,
    int n_edges) {
  __shared__ int hist[256];
  __shared__ int cur[256];
  const int t = threadIdx.x;
  const int base = blockIdx.x * SC_EPB;
  const int cnt = min(SC_EPB, n_edges - base);

  hist[t] = 0;
  __syncthreads();
  for (int j = t; j < cnt; j += 256) {
    atomicAdd(&hist[dst[base + j] >> 8], 1);
  }
  __syncthreads();
  const int h = hist[t];
  if (h > 0) cur[t] = atomicAdd(&bcur[t], h);
  __syncthreads();
  for (int j = t; j < cnt; j += 256) {
    const int e = base + j;
    const int d = dst[e];
    const int p = atomicAdd(&cur[d >> 8], 1);
    staged_pair[p] = make_int2(src[e], __float_as_int(ev[e]));
    staged_dst[p] = d;
  }
}

// Bucket phase 2: one block per bucket; exact CSR position via LDS cursors;
// stores land in the bucket's ~32KB contiguous window (L2-local).
__global__ __launch_bounds__(256) void bucket_finalize(
    const int2* __restrict__ staged_pair, const int* __restrict__ staged_dst,
    const int* __restrict__ off, int2* __restrict__ pairs, int n_nodes) {
  __shared__ int cur[256];
  const int t = threadIdx.x;
  const int lo = blockIdx.x << 8;
  const int node = lo + t;
  if (node < n_nodes) cur[t] = off[node];
  __syncthreads();
  const int beg = off[lo];
  const int end = off[min(n_nodes, lo + 256)];
  for (int j = beg + t; j < end; j += 256) {
    const int d = staged_dst[j];
    const int p = atomicAdd(&cur[d - lo], 1);
    pairs[p] = staged_pair[j];
  }
}

// ---------------------------------------------------------------------------
// Gather-reduce over bf16 support: 32 lanes per dst node, lane owns 4 cols.
// ---------------------------------------------------------------------------
__global__ __launch_bounds__(256) void gather_nodes(
    const unsigned short* __restrict__ supb, const int* __restrict__ off,
    const int2* __restrict__ pairs, const float* __restrict__ bias,
    float* __restrict__ out, int n_nodes) {
  const int d = blockIdx.x * 8 + (threadIdx.x >> 5);
  const int lane = threadIdx.x & 31;  // cols lane*4 .. lane*4+3
  if (d >= n_nodes) return;

  const int beg = off[d];
  const int end = off[d + 1];
  const uint2* sup = (const uint2*)supb;

  float a0 = 0.f, a1 = 0.f, a2 = 0.f, a3 = 0.f;
  int i = beg;
  for (; i + 2 <= end; i += 2) {
    const int2 p0 = pairs[i];
    const int2 p1 = pairs[i + 1];
    const uint2 r0 = sup[(size_t)p0.x * 32 + lane];
    const uint2 r1 = sup[(size_t)p1.x * 32 + lane];
    const float v0 = __int_as_float(p0.y);
    const float v1 = __int_as_float(p1.y);
    a0 += v0 * bf_lo(r0.x) + v1 * bf_lo(r1.x);
    a1 += v0 * bf_hi(r0.x) + v1 * bf_hi(r1.x);
    a2 += v0 * bf_lo(r0.y) + v1 * bf_lo(r1.y);
    a3 += v0 * bf_hi(r0.y) + v1 * bf_hi(r1.y);
  }
  if (i < end) {
    const int2 p0 = pairs[i];
    const uint2 r0 = sup[(size_t)p0.x * 32 + lane];
    const float v0 = __int_as_float(p0.y);
    a0 += v0 * bf_lo(r0.x);
    a1 += v0 * bf_hi(r0.x);
    a2 += v0 * bf_lo(r0.y);
    a3 += v0 * bf_hi(r0.y);
  }

  const float4 bv = ((const float4*)bias)[lane];
  ((float4*)out)[(size_t)d * 32 + lane] =
      make_float4(a0 + bv.x, a1 + bv.y, a2 + bv.z, a3 + bv.w);
}

extern "C" void kernel_launch(void* const* d_in, const int* in_sizes, int n_in,
                              void* d_out, int out_size, void* d_ws, size_t ws_size,
                              hipStream_t stream) {
  const float* x    = (const float*)d_in[0];
  const float* w    = (const float*)d_in[1];
  const float* bias = (const float*)d_in[2];
  const int*   src  = (const int*)d_in[3];
  const int*   dst  = (const int*)d_in[4];
  const float* ev   = (const float*)d_in[5];
  float* out = (float*)d_out;

  const int n_nodes = in_sizes[0] / D;
  const int n_edges = in_sizes[3];

  // workspace layout
  const size_t nn_pad = ((size_t)n_nodes + 16) & ~15ULL;
  unsigned short* supb = (unsigned short*)d_ws;        // n_nodes*D bf16 (12.8MB)
  unsigned short* wT = supb + (size_t)n_nodes * D;     // D*D bf16 (32 KB)
  int* deg  = (int*)(wT + D * D);                      // nn_pad
  int* off  = deg + nn_pad;                            // nn_pad (incl off[n])
  int* bsum = off + nn_pad;                            // 64
  int* bcur = bsum + 64;                               // 256
  int2* pairs = (int2*)(bcur + 256);                   // n_edges int2 (6.4MB)
  int2* staged_pair = pairs + n_edges;                 // n_edges int2 (6.4MB)
  int* staged_dst = (int*)(staged_pair + n_edges);     // n_edges int  (3.2MB)

  const int eb = (n_edges + 255) / 256;
  const int sblocks = (n_nodes + 4095) / 4096;         // 13
  const int nbuckets = (n_nodes + 255) / 256;          // 196
  const int scb = (n_edges + SC_EPB - 1) / SC_EPB;     // 196

  // CSR build
  hipMemsetAsync(deg, 0, n_nodes * sizeof(int), stream);
  hist_dst<<<eb, 256, 0, stream>>>(dst, deg, n_edges);
  scan_block_sums<<<sblocks, 256, 0, stream>>>(deg, bsum, n_nodes);
  scan_bsums<<<1, 64, 0, stream>>>(bsum, off, n_nodes, sblocks);
  scan_chunks<<<sblocks, 256, 0, stream>>>(deg, bsum, off, bcur, n_nodes);
  bucket_scatter<<<scb, 256, 0, stream>>>(src, dst, ev, bcur,
                                          staged_pair, staged_dst, n_edges);
  bucket_finalize<<<nbuckets, 256, 0, stream>>>(staged_pair, staged_dst, off,
                                                pairs, n_nodes);

  // dense projection (bf16 MFMA)
  conv_wT<<<(D * D + 255) / 256, 256, 0, stream>>>(w, wT);
  gemm_xw_mfma<<<(n_nodes + 63) / 64, 256, 0, stream>>>(x, wT, supb, n_nodes);

  // gather-reduce (+bias), atomic-free
  gather_nodes<<<(n_nodes + 7) / 8, 256, 0, stream>>>(
      supb, off, pairs, bias, out, n_nodes);
}